// Round 5
// baseline (402.101 us; speedup 1.0000x reference)
//
#include <hip/hip_runtime.h>
#include <stdint.h>
#include <math.h>

// ---------------------------------------------------------------------------
// MultiheadSdpaDiff3 round 9.
// - flash: exact round-7 body (verified 92.8us; round-8 counted-vmcnt variant
//   regressed +9us -> reverted).
// - GEMM1: gemm256_kernel (round-8, kept).
// - GEMM2/3: new gemm_bt2_kernel 128x256 tile, BK=32, depth-3 circular LDS
//   pipeline, counted vmcnt(3), 1 barrier/K-tile, 2 blocks/CU.
// ws layout (bytes):
//   xb   @ 0          : 16777216   (x as bf16 [4096][2048])
//   Wtq  @ 16777216   : 8388608    (Wq^T bf16 [N][K])
//   Wtk  @ 25165824   : 8388608    (contiguous after Wtq -> merged QK gemm)
//   Wtv  @ 33554432   : 8388608
//   Wto  @ 41943040   : 8388608
//   QKb  @ 50331648   : 33554432   (bf16 [4096][4096]: cols 0-2047 Q, 2048-4095 K)
//   Vt   @ 83886080   : 16777216   (bf16 [2048 e][4096 bt] = V^T, from gemm)
//   o12b @ 100663296  : 33554432   (bf16 [c][bt][h*256+e])
//   ob   @ 134217728  : 16777216   (combined+rmsnormed bf16 [4096][2048])
//   lam  @ 150994944  : 256
// ---------------------------------------------------------------------------

typedef unsigned short u16;
typedef short bf16x8 __attribute__((ext_vector_type(8)));
typedef float f32x4 __attribute__((ext_vector_type(4)));

typedef uint32_t __attribute__((address_space(1))) as1_u32;
typedef uint32_t __attribute__((address_space(3))) as3_u32;

#define LAMBDA_INIT 0.78360576653162453f

__device__ __forceinline__ u16 f2bf(float f) {
  uint32_t u = __float_as_uint(f);
  u += 0x7FFFu + ((u >> 16) & 1u);   // RNE
  return (u16)(u >> 16);
}
__device__ __forceinline__ float bf2f(u16 v) {
  return __uint_as_float(((uint32_t)v) << 16);
}

__device__ __forceinline__ void async16(u16* lds, const u16* g) {
  __builtin_amdgcn_global_load_lds((const as1_u32*)(uintptr_t)g,
                                   (as3_u32*)(uint32_t)(uintptr_t)lds, 16, 0, 0);
}

__device__ __forceinline__ f32x4 mfma16(bf16x8 a, bf16x8 b, f32x4 c) {
  return __builtin_amdgcn_mfma_f32_16x16x32_bf16(a, b, c, 0, 0, 0);
}

// --------------------------- prep kernels ----------------------------------

__global__ void cast_x_kernel(const float* __restrict__ x, u16* __restrict__ xb, int n4) {
  int i = blockIdx.x * 256 + threadIdx.x;
  if (i < n4) {
    float4 v = ((const float4*)x)[i];
    ushort4 o;
    o.x = f2bf(v.x); o.y = f2bf(v.y); o.z = f2bf(v.z); o.w = f2bf(v.w);
    ((ushort4*)xb)[i] = o;
  }
}

// Wt[n][k] = bf16(W[k][n]); W is [2048][2048] fp32. 4 matrices via blockIdx.z.
__global__ void transpose_w4_kernel(const float* __restrict__ W0, const float* __restrict__ W1,
                                    const float* __restrict__ W2, const float* __restrict__ W3,
                                    u16* __restrict__ Wt4) {
  __shared__ float tile[32][33];
  int z = blockIdx.z;
  const float* W = (z == 0) ? W0 : (z == 1) ? W1 : (z == 2) ? W2 : W3;
  u16* Wt = Wt4 + (size_t)z * 4194304;
  int tx = threadIdx.x, ty = threadIdx.y;
  int c0 = blockIdx.x * 32, r0 = blockIdx.y * 32;
#pragma unroll
  for (int i = 0; i < 32; i += 8)
    tile[ty + i][tx] = W[(size_t)(r0 + ty + i) * 2048 + c0 + tx];
  __syncthreads();
#pragma unroll
  for (int i = 0; i < 32; i += 8)
    Wt[(size_t)(c0 + ty + i) * 2048 + r0 + tx] = f2bf(tile[tx][ty + i]);
}

__global__ void lam_kernel(const float* __restrict__ lq1, const float* __restrict__ lk1,
                           const float* __restrict__ lq2, const float* __restrict__ lk2,
                           float* __restrict__ out) {
  int L = threadIdx.x;  // 64 threads
  float d1 = lq1[L] * lk1[L] + lq1[L + 64] * lk1[L + 64];
  float d2 = lq2[L] * lk2[L] + lq2[L + 64] * lk2[L + 64];
#pragma unroll
  for (int m = 1; m < 64; m <<= 1) {
    d1 += __shfl_xor(d1, m);
    d2 += __shfl_xor(d2, m);
  }
  if (L == 0) out[0] = __expf(d1) - __expf(d2) + LAMBDA_INIT;
}

// ----------------- GEMM 256x256 deep-pipelined (GEMM1) ---------------------
// 512 thr = 8 waves (2M x 4N); per-wave C = 128x64. BK=32. LDS: 4-deep
// circular buffer of (A 256x32 + B 256x32) bf16 = 128 KiB. Main loop: one
// barrier per K-tile, s_waitcnt vmcnt(8) steady state (tile t+1 landed;
// t+2/t+3 loads stay in flight across the barrier - T4).

__device__ __forceinline__ void stage256(const u16* base, int K, int k0, u16* lds, int t_) {
#pragma unroll
  for (int i = 0; i < 2; i++) {
    int s = t_ + i * 512;
    int row = s >> 2, gp = s & 3;
    int gs = gp ^ ((row >> 1) & 3);
    async16(&lds[s * 8], base + (size_t)row * K + k0 + gs * 8);
  }
}

__global__ __launch_bounds__(512, 2) void gemm256_kernel(const u16* __restrict__ A,
                                                         const u16* __restrict__ Bt,
                                                         u16* __restrict__ Cout,
                                                         int M, int N, int K) {
  __shared__ __attribute__((aligned(16))) u16 Ls[4][2][256 * 32];
  int t_ = threadIdx.x;
  int lane = t_ & 63, w = t_ >> 6;
  int lr = lane & 15, lq = lane >> 4;
  int m0 = blockIdx.y * 256, n0 = blockIdx.x * 256;
  int wm = (w >> 2) * 128, wn = (w & 3) * 64;
  const u16* Ab = A + (size_t)m0 * K;
  const u16* Bb = Bt + (size_t)n0 * K;
  int NT = K >> 5;
  f32x4 acc[8][4] = {};

  // prologue: stage tiles 0,1,2 (12 loads/thread)
#pragma unroll
  for (int p = 0; p < 3; p++) {
    stage256(Ab, K, p * 32, &Ls[p][0][0], t_);
    stage256(Bb, K, p * 32, &Ls[p][1][0], t_);
  }
  asm volatile("s_waitcnt vmcnt(8)" ::: "memory");   // tile 0 landed
  __builtin_amdgcn_s_barrier();
  __builtin_amdgcn_sched_barrier(0);

#pragma unroll 1
  for (int t = 0; t < NT; t++) {
    int d = t & 3;
    const u16* As_ = &Ls[d][0][0];
    const u16* Bs_ = &Ls[d][1][0];
    bool stg = (t + 3 < NT);
    int k0n = (t + 3) * 32;
    int dn = (t + 3) & 3;

    // ---- phase 0: B frags + A-half0 frags | stage A(t+3) | 16 MFMA ----
    bf16x8 b4[4], a0[4];
#pragma unroll
    for (int nf = 0; nf < 4; nf++) {
      int rb = wn + nf * 16 + lr;
      b4[nf] = *(const bf16x8*)&Bs_[rb * 32 + (lq ^ ((rb >> 1) & 3)) * 8];
    }
#pragma unroll
    for (int mf = 0; mf < 4; mf++) {
      int ra = wm + mf * 16 + lr;
      a0[mf] = *(const bf16x8*)&As_[ra * 32 + (lq ^ ((ra >> 1) & 3)) * 8];
    }
    if (stg) stage256(Ab, K, k0n, &Ls[dn][0][0], t_);
    __builtin_amdgcn_s_setprio(1);
#pragma unroll
    for (int mf = 0; mf < 4; mf++)
#pragma unroll
      for (int nf = 0; nf < 4; nf++)
        acc[mf][nf] = mfma16(a0[mf], b4[nf], acc[mf][nf]);
    __builtin_amdgcn_s_setprio(0);

    // ---- phase 1: A-half1 frags | stage B(t+3) | 16 MFMA ----
    bf16x8 a1[4];
#pragma unroll
    for (int mf = 0; mf < 4; mf++) {
      int ra = wm + 64 + mf * 16 + lr;
      a1[mf] = *(const bf16x8*)&As_[ra * 32 + (lq ^ ((ra >> 1) & 3)) * 8];
    }
    if (stg) stage256(Bb, K, k0n, &Ls[dn][1][0], t_);
    __builtin_amdgcn_s_setprio(1);
#pragma unroll
    for (int mf = 0; mf < 4; mf++)
#pragma unroll
      for (int nf = 0; nf < 4; nf++)
        acc[4 + mf][nf] = mfma16(a1[mf], b4[nf], acc[4 + mf][nf]);
    __builtin_amdgcn_s_setprio(0);

    // ---- tile end: counted wait (never drain in steady state) ----
    if (t < NT - 3)      asm volatile("s_waitcnt vmcnt(8)" ::: "memory");
    else if (t < NT - 2) asm volatile("s_waitcnt vmcnt(4)" ::: "memory");
    else                 asm volatile("s_waitcnt vmcnt(0)" ::: "memory");
    __builtin_amdgcn_s_barrier();
    __builtin_amdgcn_sched_barrier(0);
  }

  // epilogue
#pragma unroll
  for (int mf = 0; mf < 8; mf++)
#pragma unroll
    for (int nf = 0; nf < 4; nf++)
#pragma unroll
      for (int r = 0; r < 4; r++) {
        int row = m0 + wm + mf * 16 + lq * 4 + r;
        int col = n0 + wn + nf * 16 + lr;
        Cout[(size_t)row * N + col] = f2bf(acc[mf][nf][r]);
      }
}

// ----------------- GEMM 128x256 deep-pipelined (GEMM2/3) -------------------
// 512 thr = 8 waves (2M x 4N); per-wave C = 64x64 (acc[4][4] = 64 VGPR).
// BK=32. LDS: depth-3 circular (A 128x32 + B 256x32) = 72 KiB -> 2 blocks/CU
// at launch_bounds(512,4). Counted vmcnt(3): tile t+2's 3 loads stay in
// flight across the single per-tile barrier. 16 MFMA per wave per barrier.

__device__ __forceinline__ void stageA2(const u16* base, int K, int k0, u16* lds, int t_) {
  int row = t_ >> 2, gp = t_ & 3;
  int gs = gp ^ ((row >> 1) & 3);
  async16(&lds[t_ * 8], base + (size_t)row * K + k0 + gs * 8);
}
__device__ __forceinline__ void stageB2(const u16* base, int K, int k0, u16* lds, int t_) {
#pragma unroll
  for (int i = 0; i < 2; i++) {
    int s = t_ + i * 512;
    int row = s >> 2, gp = s & 3;
    int gs = gp ^ ((row >> 1) & 3);
    async16(&lds[s * 8], base + (size_t)row * K + k0 + gs * 8);
  }
}

template <int OUT_BF16>
__global__ __launch_bounds__(512, 4) void gemm_bt2_kernel(const u16* __restrict__ A,
                                                          const u16* __restrict__ Bt,
                                                          void* __restrict__ Cout,
                                                          int M, int N, int K) {
  __shared__ __attribute__((aligned(16))) u16 LsA[3][128 * 32];
  __shared__ __attribute__((aligned(16))) u16 LsB[3][256 * 32];
  int t_ = threadIdx.x;
  int lane = t_ & 63, w = t_ >> 6;
  int lr = lane & 15, lq = lane >> 4;
  int m0 = blockIdx.y * 128, n0 = blockIdx.x * 256;
  int wm = (w >> 2) * 64, wn = (w & 3) * 64;
  const u16* Ab = A + (size_t)m0 * K;
  const u16* Bb = Bt + (size_t)n0 * K;
  int NT = K >> 5;
  f32x4 acc[4][4] = {};

  // prologue: stage tiles 0,1 (6 loads/thread)
#pragma unroll
  for (int p = 0; p < 2; p++) {
    stageA2(Ab, K, p * 32, &LsA[p][0], t_);
    stageB2(Bb, K, p * 32, &LsB[p][0], t_);
  }
  asm volatile("s_waitcnt vmcnt(3)" ::: "memory");   // tile 0 landed
  __builtin_amdgcn_s_barrier();
  __builtin_amdgcn_sched_barrier(0);

  int d = 0, dn = 2;
#pragma unroll 1
  for (int t = 0; t < NT; t++) {
    const u16* As_ = &LsA[d][0];
    const u16* Bs_ = &LsB[d][0];
    bool stg = (t + 2 < NT);
    if (stg) {
      int k0n = (t + 2) * 32;
      stageA2(Ab, K, k0n, &LsA[dn][0], t_);
      stageB2(Bb, K, k0n, &LsB[dn][0], t_);
    }

    bf16x8 a[4], b[4];
#pragma unroll
    for (int mf = 0; mf < 4; mf++) {
      int ra = wm + mf * 16 + lr;
      a[mf] = *(const bf16x8*)&As_[ra * 32 + (lq ^ ((ra >> 1) & 3)) * 8];
    }
#pragma unroll
    for (int nf = 0; nf < 4; nf++) {
      int rb = wn + nf * 16 + lr;
      b[nf] = *(const bf16x8*)&Bs_[rb * 32 + (lq ^ ((rb >> 1) & 3)) * 8];
    }
    __builtin_amdgcn_s_setprio(1);
#pragma unroll
    for (int mf = 0; mf < 4; mf++)
#pragma unroll
      for (int nf = 0; nf < 4; nf++)
        acc[mf][nf] = mfma16(a[mf], b[nf], acc[mf][nf]);
    __builtin_amdgcn_s_setprio(0);

    if (t < NT - 1) {
      if (stg) asm volatile("s_waitcnt vmcnt(3)" ::: "memory");
      else     asm volatile("s_waitcnt vmcnt(0)" ::: "memory");
      __builtin_amdgcn_s_barrier();
      __builtin_amdgcn_sched_barrier(0);
    }

    d = (d == 2) ? 0 : d + 1;
    dn = (dn == 2) ? 0 : dn + 1;
  }

  // epilogue
#pragma unroll
  for (int mf = 0; mf < 4; mf++)
#pragma unroll
    for (int nf = 0; nf < 4; nf++)
#pragma unroll
      for (int r = 0; r < 4; r++) {
        int row = m0 + wm + mf * 16 + lq * 4 + r;
        int col = n0 + wn + nf * 16 + lr;
        if (OUT_BF16)
          ((u16*)Cout)[(size_t)row * N + col] = f2bf(acc[mf][nf][r]);
        else
          ((float*)Cout)[(size_t)row * N + col] = acc[mf][nf][r];
      }
}

// --------------------------- flash attention -------------------------------
// Round-7 body exactly (verified 92.8us): KVBLK=64, K double-buffered, V
// single-buffered (staged intra-step; mid-step __syncthreads drains V DMA).
// Defer-max (T13) + setprio around PV MFMA cluster (T5).
// K LDS: [64 rows][16 granules], granule low-3 XOR row&7.
// V LDS: [256 e][8 granules of 8 kv], granule XOR e&7.
// P LDS: per wave [16 rows][88 u16].

struct FlashCtx {
  const u16* Qbase;
  const u16* Kbase;
  const u16* Vbase;
  int t, w, lr, lq;
};

__device__ __forceinline__ void stage_k(const FlashCtx& cx, int jc, u16* Kn) {
#pragma unroll
  for (int i = 0; i < 4; i++) {
    int q = cx.t + i * 256;
    int row = q >> 4, gp = q & 15;
    int gg = (gp & 8) | ((gp & 7) ^ (row & 7));
    async16(&Kn[q * 8], cx.Kbase + (size_t)(jc + row) * 4096 + gg * 8);
  }
}

__device__ __forceinline__ void stage_v(const FlashCtx& cx, int jc, u16* Vs) {
#pragma unroll
  for (int i = 0; i < 8; i++) {
    int q = cx.t + i * 256;
    int e = q >> 3, gp = q & 7;
    int gg = gp ^ (e & 7);
    async16(&Vs[q * 8], cx.Vbase + (size_t)e * 4096 + jc + gg * 8);
  }
}

__global__ __launch_bounds__(256, 2) void flash_diff_kernel(const u16* __restrict__ QKb,
                                                            const u16* __restrict__ Vt,
                                                            u16* __restrict__ o12b) {
  __shared__ __attribute__((aligned(16))) u16 Ks0[64 * 128];
  __shared__ __attribute__((aligned(16))) u16 Ks1[64 * 128];
  __shared__ __attribute__((aligned(16))) u16 Vs[256 * 64];
  __shared__ __attribute__((aligned(16))) u16 Ps[4][16 * 88];

  int t = threadIdx.x;
  FlashCtx cx;
  cx.t = t; cx.w = t >> 6;
  cx.lr = t & 15; cx.lq = (t >> 4) & 3;

  // XCD-affine decode: group g=(bh,c) pinned to XCD g&7
  int idx = blockIdx.x;                 // 0..511
  int xcd = idx & 7, slot = idx >> 3;   // slot 0..63
  int pairI = slot & 15, ghi = slot >> 4;
  int g = ghi * 8 + xcd;                // 0..31
  int bh = g >> 1, c = g & 1;
  int b = bh >> 3, h = bh & 7;

  cx.Qbase = QKb + (size_t)b * 2048 * 4096 + h * 256 + c * 128;
  cx.Kbase = cx.Qbase + 2048;
  cx.Vbase = Vt + (size_t)(h * 256) * 4096 + b * 2048;
  u16* Op = o12b + (size_t)c * (4096ull * 2048) + (size_t)b * 2048 * 2048 + h * 256;
  u16* PsW = Ps[cx.w];

  u16* Kc = Ks0;
  u16* Kn = Ks1;

  // prologue: stage K tile 0 of phase 0 into buf0
  stage_k(cx, 0, Kc);

#pragma unroll 1
  for (int phase = 0; phase < 2; phase++) {
    int qi = phase ? (31 - pairI) : pairI;
    int q0 = qi * 64;
    int nst = qi + 1;

    bf16x8 qa[4];
#pragma unroll
    for (int ks = 0; ks < 4; ks++)
      qa[ks] = *(const bf16x8*)&cx.Qbase[(size_t)(q0 + cx.w * 16 + cx.lr) * 4096 +
                                         ks * 32 + cx.lq * 8];

    f32x4 acc[16] = {};
    f32x4 lacc = {};
    float m_ = -INFINITY;
    int rowmax = q0 + cx.w * 16 + 15;

#pragma unroll 1
    for (int j = 0; j < nst; j++) {
      int jc = j * 64;
      int njc = (j + 1 < nst) ? (j + 1) * 64 : (phase == 0 ? 0 : -1);

      __syncthreads();                     // A: joins prev PV; drains prev DMA
      if (njc >= 0) stage_k(cx, njc, Kn);  // overlaps with QK+softmax below
      stage_v(cx, jc, Vs);                 // drained at barrier B

      bool act = (jc <= rowmax);           // wave-uniform
      if (act) {
        // S = Q K^T : 16 rows x 64 cols per wave
        f32x4 sacc[4] = {};
#pragma unroll
        for (int ks = 0; ks < 4; ks++) {
#pragma unroll
          for (int ni = 0; ni < 4; ni++) {
            int row = ni * 16 + cx.lr;
            int gk = ks * 4 + cx.lq;
            int gp = (gk & 8) | ((gk & 7) ^ (row & 7));
            bf16x8 kb = *(const bf16x8*)&Kc[row * 128 + gp * 8];
            sacc[ni] = mfma16(qa[ks], kb, sacc[ni]);
          }
        }

        // scores in exp2 domain + causal mask (diag tiles only)
        const float k2 = 0.12753257550036097f;   // log2(e)/sqrt(128)
        float s2[4][4];
        bool diag = (jc + 63 > q0 + cx.w * 16);
#pragma unroll
        for (int ni = 0; ni < 4; ni++)
#pragma unroll
          for (int r = 0; r < 4; r++) {
            float v = sacc[ni][r] * k2;
            if (diag) {
              int colg = jc + ni * 16 + cx.lr;
              int rowg = q0 + cx.w * 16 + cx.lq * 4 + r;
              if (colg > rowg) v = -INFINITY;
            }
            s2[ni][r] = v;
          }

        // defer-max: in-lane max + one ballot; slow path only on big jumps
        float sm = fmaxf(
            fmaxf(fmaxf(fmaxf(s2[0][0], s2[0][1]), fmaxf(s2[0][2], s2[0][3])),
                  fmaxf(fmaxf(s2[1][0], s2[1][1]), fmaxf(s2[1][2], s2[1][3]))),
            fmaxf(fmaxf(fmaxf(s2[2][0], s2[2][1]), fmaxf(s2[2][2], s2[2][3])),
                  fmaxf(fmaxf(s2[3][0], s2[3][1]), fmaxf(s2[3][2], s2[3][3]))));
        float mo = m_;
        if (__any(sm > mo + 8.0f)) {         // wave-uniform branch
          float mv = sm;
          mv = fmaxf(mv, __shfl_xor(mv, 1));
          mv = fmaxf(mv, __shfl_xor(mv, 2));
          mv = fmaxf(mv, __shfl_xor(mv, 4));
          mv = fmaxf(mv, __shfl_xor(mv, 8));
          mv = fmaxf(mv, __shfl_xor(mv, 16));
          mv = fmaxf(mv, __shfl_xor(mv, 32));
          float mn = fmaxf(mo, mv);          // == mv here
          float a = __builtin_amdgcn_exp2f(mo - mn);   // -inf -> 0
#pragma unroll
          for (int ei = 0; ei < 16; ei++)
#pragma unroll
            for (int r = 0; r < 4; r++) acc[ei][r] *= a;
#pragma unroll
          for (int r = 0; r < 4; r++) lacc[r] *= a;
          m_ = mn;
          mo = mn;
        }

        // P (truncated bf16; consistent with l via ones-MFMA); bounded by 2^8
#pragma unroll
        for (int ni = 0; ni < 4; ni++)
#pragma unroll
          for (int r = 0; r < 4; r++) {
            float p = __builtin_amdgcn_exp2f(s2[ni][r] - mo);
            PsW[(cx.lq * 4 + r) * 88 + ni * 16 + cx.lr] =
                (u16)(__float_as_uint(p) >> 16);
          }
      }

      __syncthreads();                     // B: drains V(jc), K(njc); P visible
      if (act) {
        const bf16x8 onesb = {0x3F80, 0x3F80, 0x3F80, 0x3F80,
                              0x3F80, 0x3F80, 0x3F80, 0x3F80};
        bf16x8 pa0 = *(const bf16x8*)&PsW[cx.lr * 88 + cx.lq * 8];
        bf16x8 pa1 = *(const bf16x8*)&PsW[cx.lr * 88 + 32 + cx.lq * 8];
        __builtin_amdgcn_s_setprio(1);
#pragma unroll
        for (int ei = 0; ei < 16; ei++) {
          int e = ei * 16 + cx.lr;
          int g0 = cx.lq ^ (e & 7);
          int g1 = g0 ^ 4;                 // (4+lq) ^ (e&7)
          bf16x8 vb0 = *(const bf16x8*)&Vs[e * 64 + g0 * 8];
          bf16x8 vb1 = *(const bf16x8*)&Vs[e * 64 + g1 * 8];
          acc[ei] = mfma16(pa0, vb0, acc[ei]);
          acc[ei] = mfma16(pa1, vb1, acc[ei]);
        }
        lacc = mfma16(pa0, onesb, lacc);
        lacc = mfma16(pa1, onesb, lacc);
        __builtin_amdgcn_s_setprio(0);
      }

      u16* tmp = Kc; Kc = Kn; Kn = tmp;
    }

    // epilogue: o12b[c][b*2048+row][h*256+e]
#pragma unroll
    for (int r = 0; r < 4; r++) {
      float inv = 1.0f / lacc[r];
      int row = q0 + cx.w * 16 + cx.lq * 4 + r;
#pragma unroll
      for (int ei = 0; ei < 16; ei++)
        Op[(size_t)row * 2048 + ei * 16 + cx.lr] = f2bf(acc[ei][r] * inv);
    }
  }
}

// --------------------------- combine + RMSNorm -----------------------------
__global__ void combine_kernel(const u16* __restrict__ o12b, const float* __restrict__ lamp,
                               const float* __restrict__ g, u16* __restrict__ ob) {
  __shared__ float red[4];
  int t = threadIdx.x;
  int grp = blockIdx.x;  // (b*2048+tt)*8 + h
  size_t idx = (size_t)grp * 256 + t;
  const size_t comp = 4096ull * 2048;
  float lam = lamp[0];
  float v = bf2f(o12b[idx]) - lam * bf2f(o12b[idx + comp]);
  float ss = v * v;
  ss += __shfl_xor(ss, 1);
  ss += __shfl_xor(ss, 2);
  ss += __shfl_xor(ss, 4);
  ss += __shfl_xor(ss, 8);
  ss += __shfl_xor(ss, 16);
  ss += __shfl_xor(ss, 32);
  if ((t & 63) == 0) red[t >> 6] = ss;
  __syncthreads();
  float tot = red[0] + red[1] + red[2] + red[3];
  float scale = rsqrtf(tot * (1.0f / 256.0f) + 1e-5f) * (1.0f - LAMBDA_INIT);
  ob[(size_t)(grp >> 3) * 2048 + (grp & 7) * 256 + t] = f2bf(v * scale * g[t]);
}

// ---------------------------------------------------------------------------

extern "C" void kernel_launch(void* const* d_in, const int* in_sizes, int n_in,
                              void* d_out, int out_size, void* d_ws, size_t ws_size,
                              hipStream_t stream) {
  const float* x   = (const float*)d_in[0];
  const float* Wq  = (const float*)d_in[1];
  const float* Wk  = (const float*)d_in[2];
  const float* Wv  = (const float*)d_in[3];
  const float* Wo  = (const float*)d_in[4];
  const float* lq1 = (const float*)d_in[5];
  const float* lk1 = (const float*)d_in[6];
  const float* lq2 = (const float*)d_in[7];
  const float* lk2 = (const float*)d_in[8];
  const float* g   = (const float*)d_in[9];

  char* ws = (char*)d_ws;
  u16* xb    = (u16*)(ws);
  u16* Wtq   = (u16*)(ws + 16777216);
  u16* Wtv   = (u16*)(ws + 33554432);
  u16* Wto   = (u16*)(ws + 41943040);
  u16* QKb   = (u16*)(ws + 50331648);
  u16* Vt    = (u16*)(ws + 83886080);
  u16* o12b  = (u16*)(ws + 100663296);
  u16* ob    = (u16*)(ws + 134217728);
  float* lamp = (float*)(ws + 150994944);

  cast_x_kernel<<<8192, 256, 0, stream>>>(x, xb, 2097152);
  transpose_w4_kernel<<<dim3(64, 64, 4), dim3(32, 8), 0, stream>>>(Wq, Wk, Wv, Wo, Wtq);
  lam_kernel<<<1, 64, 0, stream>>>(lq1, lk1, lq2, lk2, lamp);

  // [Q|K] = x @ [Wq|Wk] : M=4096, N=4096 (Wtq,Wtk contiguous) - 256^2 pipeline
  gemm256_kernel<<<dim3(16, 16), 512, 0, stream>>>(xb, Wtq, QKb, 4096, 4096, 2048);
  // V^T directly: C[e][bt] = sum_k Wv[k][e] x[bt][k]  (M=2048, N=4096)
  gemm_bt2_kernel<1><<<dim3(16, 16), 512, 0, stream>>>(Wtv, xb, Vt, 2048, 4096, 2048);

  flash_diff_kernel<<<512, 256, 0, stream>>>(QKb, Vt, o12b);
  combine_kernel<<<32768, 256, 0, stream>>>(o12b, lamp, g, ob);
  gemm_bt2_kernel<0><<<dim3(8, 32), 512, 0, stream>>>(ob, Wto, (float*)d_out, 4096, 2048, 2048);
}

// Round 6
// 395.144 us; speedup vs baseline: 1.0176x; 1.0176x over previous
//
#include <hip/hip_runtime.h>
#include <stdint.h>
#include <math.h>

// ---------------------------------------------------------------------------
// MultiheadSdpaDiff3 round 10.
// = round-8 config (gemm256 for QKb, gemm_bt BK=64 for GEMM2/3, round-7 flash
//   body) + two locality fixes:
//   (a) flash block decode: XCD = h, matching gemm256's writer XCD for both
//       the Q col-tile (bx=h) and K col-tile (bx=8+h) of head h.
//   (b) launch order: Vt GEMM first, QKb GEMM immediately before flash, so
//       QKb (4 MB/XCD = one L2) is still resident per-XCD when flash reads.
// ws layout (bytes):
//   xb   @ 0          : 16777216   (x as bf16 [4096][2048])
//   Wtq  @ 16777216   : 8388608    (Wq^T bf16 [N][K])
//   Wtk  @ 25165824   : 8388608    (contiguous after Wtq -> merged QK gemm)
//   Wtv  @ 33554432   : 8388608
//   Wto  @ 41943040   : 8388608
//   QKb  @ 50331648   : 33554432   (bf16 [4096][4096]: cols 0-2047 Q, 2048-4095 K)
//   Vt   @ 83886080   : 16777216   (bf16 [2048 e][4096 bt] = V^T, from gemm)
//   o12b @ 100663296  : 33554432   (bf16 [c][bt][h*256+e])
//   ob   @ 134217728  : 16777216   (combined+rmsnormed bf16 [4096][2048])
//   lam  @ 150994944  : 256
// ---------------------------------------------------------------------------

typedef unsigned short u16;
typedef short bf16x8 __attribute__((ext_vector_type(8)));
typedef float f32x4 __attribute__((ext_vector_type(4)));

typedef uint32_t __attribute__((address_space(1))) as1_u32;
typedef uint32_t __attribute__((address_space(3))) as3_u32;

#define LAMBDA_INIT 0.78360576653162453f

__device__ __forceinline__ u16 f2bf(float f) {
  uint32_t u = __float_as_uint(f);
  u += 0x7FFFu + ((u >> 16) & 1u);   // RNE
  return (u16)(u >> 16);
}
__device__ __forceinline__ float bf2f(u16 v) {
  return __uint_as_float(((uint32_t)v) << 16);
}

__device__ __forceinline__ void async16(u16* lds, const u16* g) {
  __builtin_amdgcn_global_load_lds((const as1_u32*)(uintptr_t)g,
                                   (as3_u32*)(uint32_t)(uintptr_t)lds, 16, 0, 0);
}

__device__ __forceinline__ f32x4 mfma16(bf16x8 a, bf16x8 b, f32x4 c) {
  return __builtin_amdgcn_mfma_f32_16x16x32_bf16(a, b, c, 0, 0, 0);
}

// --------------------------- prep kernels ----------------------------------

__global__ void cast_x_kernel(const float* __restrict__ x, u16* __restrict__ xb, int n4) {
  int i = blockIdx.x * 256 + threadIdx.x;
  if (i < n4) {
    float4 v = ((const float4*)x)[i];
    ushort4 o;
    o.x = f2bf(v.x); o.y = f2bf(v.y); o.z = f2bf(v.z); o.w = f2bf(v.w);
    ((ushort4*)xb)[i] = o;
  }
}

// Wt[n][k] = bf16(W[k][n]); W is [2048][2048] fp32. 4 matrices via blockIdx.z.
__global__ void transpose_w4_kernel(const float* __restrict__ W0, const float* __restrict__ W1,
                                    const float* __restrict__ W2, const float* __restrict__ W3,
                                    u16* __restrict__ Wt4) {
  __shared__ float tile[32][33];
  int z = blockIdx.z;
  const float* W = (z == 0) ? W0 : (z == 1) ? W1 : (z == 2) ? W2 : W3;
  u16* Wt = Wt4 + (size_t)z * 4194304;
  int tx = threadIdx.x, ty = threadIdx.y;
  int c0 = blockIdx.x * 32, r0 = blockIdx.y * 32;
#pragma unroll
  for (int i = 0; i < 32; i += 8)
    tile[ty + i][tx] = W[(size_t)(r0 + ty + i) * 2048 + c0 + tx];
  __syncthreads();
#pragma unroll
  for (int i = 0; i < 32; i += 8)
    Wt[(size_t)(c0 + ty + i) * 2048 + r0 + tx] = f2bf(tile[tx][ty + i]);
}

__global__ void lam_kernel(const float* __restrict__ lq1, const float* __restrict__ lk1,
                           const float* __restrict__ lq2, const float* __restrict__ lk2,
                           float* __restrict__ out) {
  int L = threadIdx.x;  // 64 threads
  float d1 = lq1[L] * lk1[L] + lq1[L + 64] * lk1[L + 64];
  float d2 = lq2[L] * lk2[L] + lq2[L + 64] * lk2[L + 64];
#pragma unroll
  for (int m = 1; m < 64; m <<= 1) {
    d1 += __shfl_xor(d1, m);
    d2 += __shfl_xor(d2, m);
  }
  if (L == 0) out[0] = __expf(d1) - __expf(d2) + LAMBDA_INIT;
}

// ----------------- GEMM 256x256 deep-pipelined (GEMM1) ---------------------
// 512 thr = 8 waves (2M x 4N); per-wave C = 128x64. BK=32. LDS: 4-deep
// circular buffer of (A 256x32 + B 256x32) bf16 = 128 KiB. Main loop: one
// barrier per K-tile, s_waitcnt vmcnt(8) steady state (tile t+1 landed;
// t+2/t+3 loads stay in flight across the barrier - T4).
// XCD note: linear dispatch on the 16x16 grid puts every writer of col-tile
// bx on XCD bx&7 -> Q cols of head h (bx=h) and K cols (bx=8+h) both land in
// XCD h's L2; flash consumes with xcd=h.

__device__ __forceinline__ void stage256(const u16* base, int K, int k0, u16* lds, int t_) {
#pragma unroll
  for (int i = 0; i < 2; i++) {
    int s = t_ + i * 512;
    int row = s >> 2, gp = s & 3;
    int gs = gp ^ ((row >> 1) & 3);
    async16(&lds[s * 8], base + (size_t)row * K + k0 + gs * 8);
  }
}

__global__ __launch_bounds__(512, 2) void gemm256_kernel(const u16* __restrict__ A,
                                                         const u16* __restrict__ Bt,
                                                         u16* __restrict__ Cout,
                                                         int M, int N, int K) {
  __shared__ __attribute__((aligned(16))) u16 Ls[4][2][256 * 32];
  int t_ = threadIdx.x;
  int lane = t_ & 63, w = t_ >> 6;
  int lr = lane & 15, lq = lane >> 4;
  int m0 = blockIdx.y * 256, n0 = blockIdx.x * 256;
  int wm = (w >> 2) * 128, wn = (w & 3) * 64;
  const u16* Ab = A + (size_t)m0 * K;
  const u16* Bb = Bt + (size_t)n0 * K;
  int NT = K >> 5;
  f32x4 acc[8][4] = {};

  // prologue: stage tiles 0,1,2 (12 loads/thread)
#pragma unroll
  for (int p = 0; p < 3; p++) {
    stage256(Ab, K, p * 32, &Ls[p][0][0], t_);
    stage256(Bb, K, p * 32, &Ls[p][1][0], t_);
  }
  asm volatile("s_waitcnt vmcnt(8)" ::: "memory");   // tile 0 landed
  __builtin_amdgcn_s_barrier();
  __builtin_amdgcn_sched_barrier(0);

#pragma unroll 1
  for (int t = 0; t < NT; t++) {
    int d = t & 3;
    const u16* As_ = &Ls[d][0][0];
    const u16* Bs_ = &Ls[d][1][0];
    bool stg = (t + 3 < NT);
    int k0n = (t + 3) * 32;
    int dn = (t + 3) & 3;

    // ---- phase 0: B frags + A-half0 frags | stage A(t+3) | 16 MFMA ----
    bf16x8 b4[4], a0[4];
#pragma unroll
    for (int nf = 0; nf < 4; nf++) {
      int rb = wn + nf * 16 + lr;
      b4[nf] = *(const bf16x8*)&Bs_[rb * 32 + (lq ^ ((rb >> 1) & 3)) * 8];
    }
#pragma unroll
    for (int mf = 0; mf < 4; mf++) {
      int ra = wm + mf * 16 + lr;
      a0[mf] = *(const bf16x8*)&As_[ra * 32 + (lq ^ ((ra >> 1) & 3)) * 8];
    }
    if (stg) stage256(Ab, K, k0n, &Ls[dn][0][0], t_);
    __builtin_amdgcn_s_setprio(1);
#pragma unroll
    for (int mf = 0; mf < 4; mf++)
#pragma unroll
      for (int nf = 0; nf < 4; nf++)
        acc[mf][nf] = mfma16(a0[mf], b4[nf], acc[mf][nf]);
    __builtin_amdgcn_s_setprio(0);

    // ---- phase 1: A-half1 frags | stage B(t+3) | 16 MFMA ----
    bf16x8 a1[4];
#pragma unroll
    for (int mf = 0; mf < 4; mf++) {
      int ra = wm + 64 + mf * 16 + lr;
      a1[mf] = *(const bf16x8*)&As_[ra * 32 + (lq ^ ((ra >> 1) & 3)) * 8];
    }
    if (stg) stage256(Bb, K, k0n, &Ls[dn][1][0], t_);
    __builtin_amdgcn_s_setprio(1);
#pragma unroll
    for (int mf = 0; mf < 4; mf++)
#pragma unroll
      for (int nf = 0; nf < 4; nf++)
        acc[4 + mf][nf] = mfma16(a1[mf], b4[nf], acc[4 + mf][nf]);
    __builtin_amdgcn_s_setprio(0);

    // ---- tile end: counted wait (never drain in steady state) ----
    if (t < NT - 3)      asm volatile("s_waitcnt vmcnt(8)" ::: "memory");
    else if (t < NT - 2) asm volatile("s_waitcnt vmcnt(4)" ::: "memory");
    else                 asm volatile("s_waitcnt vmcnt(0)" ::: "memory");
    __builtin_amdgcn_s_barrier();
    __builtin_amdgcn_sched_barrier(0);
  }

  // epilogue
#pragma unroll
  for (int mf = 0; mf < 8; mf++)
#pragma unroll
    for (int nf = 0; nf < 4; nf++)
#pragma unroll
      for (int r = 0; r < 4; r++) {
        int row = m0 + wm + mf * 16 + lq * 4 + r;
        int col = n0 + wn + nf * 16 + lr;
        Cout[(size_t)row * N + col] = f2bf(acc[mf][nf][r]);
      }
}

// --------------------------- GEMM (m97 + BK=64 + swizzle) ------------------
// Used for GEMM2/3 (round-8 proven config).
template <int OUT_BF16>
__global__ __launch_bounds__(256, 3) void gemm_bt_kernel(const u16* __restrict__ A,
                                                         const u16* __restrict__ Bt,
                                                         void* __restrict__ Cout,
                                                         int M, int N, int K) {
  __shared__ __attribute__((aligned(16))) u16 As[128 * 64];
  __shared__ __attribute__((aligned(16))) u16 Bs[128 * 64];
  int t = threadIdx.x;
  int lane = t & 63, w = t >> 6;
  int lr = lane & 15, lq = lane >> 4;
  int m0 = blockIdx.y * 128, n0 = blockIdx.x * 128;
  int wm = (w >> 1) * 64, wn = (w & 1) * 64;
  const u16* Ab = A + (size_t)m0 * K;
  const u16* Bb = Bt + (size_t)n0 * K;
  f32x4 acc[4][4] = {};

  for (int k0 = 0; k0 < K; k0 += 64) {
    __syncthreads();
#pragma unroll
    for (int i = 0; i < 4; i++) {
      int q = t + i * 256;
      int row = q >> 3, gp = q & 7;
      int gg = gp ^ (row & 7);
      async16(&As[q * 8], Ab + (size_t)row * K + k0 + gg * 8);
      async16(&Bs[q * 8], Bb + (size_t)row * K + k0 + gg * 8);
    }
    __syncthreads();
#pragma unroll
    for (int kk = 0; kk < 2; kk++) {
      bf16x8 a[4], b[4];
#pragma unroll
      for (int mi = 0; mi < 4; mi++) {
        int ra = wm + mi * 16 + lr;
        int rb = wn + mi * 16 + lr;
        a[mi] = *(const bf16x8*)&As[ra * 64 + ((kk * 4 + lq) ^ (ra & 7)) * 8];
        b[mi] = *(const bf16x8*)&Bs[rb * 64 + ((kk * 4 + lq) ^ (rb & 7)) * 8];
      }
#pragma unroll
      for (int mi = 0; mi < 4; mi++)
#pragma unroll
        for (int ni = 0; ni < 4; ni++)
          acc[mi][ni] = mfma16(a[mi], b[ni], acc[mi][ni]);
    }
  }
#pragma unroll
  for (int mi = 0; mi < 4; mi++) {
#pragma unroll
    for (int ni = 0; ni < 4; ni++) {
#pragma unroll
      for (int r = 0; r < 4; r++) {
        int row = m0 + wm + mi * 16 + lq * 4 + r;
        int col = n0 + wn + ni * 16 + lr;
        if (OUT_BF16)
          ((u16*)Cout)[(size_t)row * N + col] = f2bf(acc[mi][ni][r]);
        else
          ((float*)Cout)[(size_t)row * N + col] = acc[mi][ni][r];
      }
    }
  }
}

// --------------------------- flash attention -------------------------------
// Round-7 body (verified 92.8us). Round-10 change: block decode puts group
// (b,h,c) on XCD = h, matching gemm256's writer XCD for head h's Q/K col-
// tiles (bx=h and bx=8+h both dispatch on XCD h). Per-XCD QKb working set
// = 4 MB = one L2.
// K LDS: [64 rows][16 granules], granule low-3 XOR row&7.
// V LDS: [256 e][8 granules of 8 kv], granule XOR e&7.
// P LDS: per wave [16 rows][88 u16].

struct FlashCtx {
  const u16* Qbase;
  const u16* Kbase;
  const u16* Vbase;
  int t, w, lr, lq;
};

__device__ __forceinline__ void stage_k(const FlashCtx& cx, int jc, u16* Kn) {
#pragma unroll
  for (int i = 0; i < 4; i++) {
    int q = cx.t + i * 256;
    int row = q >> 4, gp = q & 15;
    int gg = (gp & 8) | ((gp & 7) ^ (row & 7));
    async16(&Kn[q * 8], cx.Kbase + (size_t)(jc + row) * 4096 + gg * 8);
  }
}

__device__ __forceinline__ void stage_v(const FlashCtx& cx, int jc, u16* Vs) {
#pragma unroll
  for (int i = 0; i < 8; i++) {
    int q = cx.t + i * 256;
    int e = q >> 3, gp = q & 7;
    int gg = gp ^ (e & 7);
    async16(&Vs[q * 8], cx.Vbase + (size_t)e * 4096 + jc + gg * 8);
  }
}

__global__ __launch_bounds__(256, 2) void flash_diff_kernel(const u16* __restrict__ QKb,
                                                            const u16* __restrict__ Vt,
                                                            u16* __restrict__ o12b) {
  __shared__ __attribute__((aligned(16))) u16 Ks0[64 * 128];
  __shared__ __attribute__((aligned(16))) u16 Ks1[64 * 128];
  __shared__ __attribute__((aligned(16))) u16 Vs[256 * 64];
  __shared__ __attribute__((aligned(16))) u16 Ps[4][16 * 88];

  int t = threadIdx.x;
  FlashCtx cx;
  cx.t = t; cx.w = t >> 6;
  cx.lr = t & 15; cx.lq = (t >> 4) & 3;

  // XCD = h decode: consumer XCD == producer XCD of head h's Q/K tiles.
  int idx = blockIdx.x;                 // 0..511
  int h = idx & 7;                      // XCD h
  int slot = idx >> 3;                  // 0..63
  int pairI = slot & 15;
  int hi2 = slot >> 4;                  // 0..3
  int b = hi2 & 1, c = hi2 >> 1;

  cx.Qbase = QKb + (size_t)b * 2048 * 4096 + h * 256 + c * 128;
  cx.Kbase = cx.Qbase + 2048;
  cx.Vbase = Vt + (size_t)(h * 256) * 4096 + b * 2048;
  u16* Op = o12b + (size_t)c * (4096ull * 2048) + (size_t)b * 2048 * 2048 + h * 256;
  u16* PsW = Ps[cx.w];

  u16* Kc = Ks0;
  u16* Kn = Ks1;

  // prologue: stage K tile 0 of phase 0 into buf0
  stage_k(cx, 0, Kc);

#pragma unroll 1
  for (int phase = 0; phase < 2; phase++) {
    int qi = phase ? (31 - pairI) : pairI;
    int q0 = qi * 64;
    int nst = qi + 1;

    bf16x8 qa[4];
#pragma unroll
    for (int ks = 0; ks < 4; ks++)
      qa[ks] = *(const bf16x8*)&cx.Qbase[(size_t)(q0 + cx.w * 16 + cx.lr) * 4096 +
                                         ks * 32 + cx.lq * 8];

    f32x4 acc[16] = {};
    f32x4 lacc = {};
    float m_ = -INFINITY;
    int rowmax = q0 + cx.w * 16 + 15;

#pragma unroll 1
    for (int j = 0; j < nst; j++) {
      int jc = j * 64;
      int njc = (j + 1 < nst) ? (j + 1) * 64 : (phase == 0 ? 0 : -1);

      __syncthreads();                     // A: joins prev PV; drains prev DMA
      if (njc >= 0) stage_k(cx, njc, Kn);  // overlaps with QK+softmax below
      stage_v(cx, jc, Vs);                 // drained at barrier B

      bool act = (jc <= rowmax);           // wave-uniform
      if (act) {
        // S = Q K^T : 16 rows x 64 cols per wave
        f32x4 sacc[4] = {};
#pragma unroll
        for (int ks = 0; ks < 4; ks++) {
#pragma unroll
          for (int ni = 0; ni < 4; ni++) {
            int row = ni * 16 + cx.lr;
            int gk = ks * 4 + cx.lq;
            int gp = (gk & 8) | ((gk & 7) ^ (row & 7));
            bf16x8 kb = *(const bf16x8*)&Kc[row * 128 + gp * 8];
            sacc[ni] = mfma16(qa[ks], kb, sacc[ni]);
          }
        }

        // scores in exp2 domain + causal mask (diag tiles only)
        const float k2 = 0.12753257550036097f;   // log2(e)/sqrt(128)
        float s2[4][4];
        bool diag = (jc + 63 > q0 + cx.w * 16);
#pragma unroll
        for (int ni = 0; ni < 4; ni++)
#pragma unroll
          for (int r = 0; r < 4; r++) {
            float v = sacc[ni][r] * k2;
            if (diag) {
              int colg = jc + ni * 16 + cx.lr;
              int rowg = q0 + cx.w * 16 + cx.lq * 4 + r;
              if (colg > rowg) v = -INFINITY;
            }
            s2[ni][r] = v;
          }

        // defer-max: in-lane max + one ballot; slow path only on big jumps
        float sm = fmaxf(
            fmaxf(fmaxf(fmaxf(s2[0][0], s2[0][1]), fmaxf(s2[0][2], s2[0][3])),
                  fmaxf(fmaxf(s2[1][0], s2[1][1]), fmaxf(s2[1][2], s2[1][3]))),
            fmaxf(fmaxf(fmaxf(s2[2][0], s2[2][1]), fmaxf(s2[2][2], s2[2][3])),
                  fmaxf(fmaxf(s2[3][0], s2[3][1]), fmaxf(s2[3][2], s2[3][3]))));
        float mo = m_;
        if (__any(sm > mo + 8.0f)) {         // wave-uniform branch
          float mv = sm;
          mv = fmaxf(mv, __shfl_xor(mv, 1));
          mv = fmaxf(mv, __shfl_xor(mv, 2));
          mv = fmaxf(mv, __shfl_xor(mv, 4));
          mv = fmaxf(mv, __shfl_xor(mv, 8));
          mv = fmaxf(mv, __shfl_xor(mv, 16));
          mv = fmaxf(mv, __shfl_xor(mv, 32));
          float mn = fmaxf(mo, mv);          // == mv here
          float a = __builtin_amdgcn_exp2f(mo - mn);   // -inf -> 0
#pragma unroll
          for (int ei = 0; ei < 16; ei++)
#pragma unroll
            for (int r = 0; r < 4; r++) acc[ei][r] *= a;
#pragma unroll
          for (int r = 0; r < 4; r++) lacc[r] *= a;
          m_ = mn;
          mo = mn;
        }

        // P (truncated bf16; consistent with l via ones-MFMA); bounded by 2^8
#pragma unroll
        for (int ni = 0; ni < 4; ni++)
#pragma unroll
          for (int r = 0; r < 4; r++) {
            float p = __builtin_amdgcn_exp2f(s2[ni][r] - mo);
            PsW[(cx.lq * 4 + r) * 88 + ni * 16 + cx.lr] =
                (u16)(__float_as_uint(p) >> 16);
          }
      }

      __syncthreads();                     // B: drains V(jc), K(njc); P visible
      if (act) {
        const bf16x8 onesb = {0x3F80, 0x3F80, 0x3F80, 0x3F80,
                              0x3F80, 0x3F80, 0x3F80, 0x3F80};
        bf16x8 pa0 = *(const bf16x8*)&PsW[cx.lr * 88 + cx.lq * 8];
        bf16x8 pa1 = *(const bf16x8*)&PsW[cx.lr * 88 + 32 + cx.lq * 8];
        __builtin_amdgcn_s_setprio(1);
#pragma unroll
        for (int ei = 0; ei < 16; ei++) {
          int e = ei * 16 + cx.lr;
          int g0 = cx.lq ^ (e & 7);
          int g1 = g0 ^ 4;                 // (4+lq) ^ (e&7)
          bf16x8 vb0 = *(const bf16x8*)&Vs[e * 64 + g0 * 8];
          bf16x8 vb1 = *(const bf16x8*)&Vs[e * 64 + g1 * 8];
          acc[ei] = mfma16(pa0, vb0, acc[ei]);
          acc[ei] = mfma16(pa1, vb1, acc[ei]);
        }
        lacc = mfma16(pa0, onesb, lacc);
        lacc = mfma16(pa1, onesb, lacc);
        __builtin_amdgcn_s_setprio(0);
      }

      u16* tmp = Kc; Kc = Kn; Kn = tmp;
    }

    // epilogue: o12b[c][b*2048+row][h*256+e]
#pragma unroll
    for (int r = 0; r < 4; r++) {
      float inv = 1.0f / lacc[r];
      int row = q0 + cx.w * 16 + cx.lq * 4 + r;
#pragma unroll
      for (int ei = 0; ei < 16; ei++)
        Op[(size_t)row * 2048 + ei * 16 + cx.lr] = f2bf(acc[ei][r] * inv);
    }
  }
}

// --------------------------- combine + RMSNorm -----------------------------
__global__ void combine_kernel(const u16* __restrict__ o12b, const float* __restrict__ lamp,
                               const float* __restrict__ g, u16* __restrict__ ob) {
  __shared__ float red[4];
  int t = threadIdx.x;
  int grp = blockIdx.x;  // (b*2048+tt)*8 + h
  size_t idx = (size_t)grp * 256 + t;
  const size_t comp = 4096ull * 2048;
  float lam = lamp[0];
  float v = bf2f(o12b[idx]) - lam * bf2f(o12b[idx + comp]);
  float ss = v * v;
  ss += __shfl_xor(ss, 1);
  ss += __shfl_xor(ss, 2);
  ss += __shfl_xor(ss, 4);
  ss += __shfl_xor(ss, 8);
  ss += __shfl_xor(ss, 16);
  ss += __shfl_xor(ss, 32);
  if ((t & 63) == 0) red[t >> 6] = ss;
  __syncthreads();
  float tot = red[0] + red[1] + red[2] + red[3];
  float scale = rsqrtf(tot * (1.0f / 256.0f) + 1e-5f) * (1.0f - LAMBDA_INIT);
  ob[(size_t)(grp >> 3) * 2048 + (grp & 7) * 256 + t] = f2bf(v * scale * g[t]);
}

// ---------------------------------------------------------------------------

extern "C" void kernel_launch(void* const* d_in, const int* in_sizes, int n_in,
                              void* d_out, int out_size, void* d_ws, size_t ws_size,
                              hipStream_t stream) {
  const float* x   = (const float*)d_in[0];
  const float* Wq  = (const float*)d_in[1];
  const float* Wk  = (const float*)d_in[2];
  const float* Wv  = (const float*)d_in[3];
  const float* Wo  = (const float*)d_in[4];
  const float* lq1 = (const float*)d_in[5];
  const float* lk1 = (const float*)d_in[6];
  const float* lq2 = (const float*)d_in[7];
  const float* lk2 = (const float*)d_in[8];
  const float* g   = (const float*)d_in[9];

  char* ws = (char*)d_ws;
  u16* xb    = (u16*)(ws);
  u16* Wtq   = (u16*)(ws + 16777216);
  u16* Wtv   = (u16*)(ws + 33554432);
  u16* Wto   = (u16*)(ws + 41943040);
  u16* QKb   = (u16*)(ws + 50331648);
  u16* Vt    = (u16*)(ws + 83886080);
  u16* o12b  = (u16*)(ws + 100663296);
  u16* ob    = (u16*)(ws + 134217728);
  float* lamp = (float*)(ws + 150994944);

  cast_x_kernel<<<8192, 256, 0, stream>>>(x, xb, 2097152);
  transpose_w4_kernel<<<dim3(64, 64, 4), dim3(32, 8), 0, stream>>>(Wq, Wk, Wv, Wo, Wtq);
  lam_kernel<<<1, 64, 0, stream>>>(lq1, lk1, lq2, lk2, lamp);

  // V^T first: C[e][bt] = sum_k Wv[k][e] x[bt][k]  (M=2048, N=4096)
  gemm_bt_kernel<1><<<dim3(32, 16), 256, 0, stream>>>(Wtv, xb, Vt, 2048, 4096, 2048);
  // [Q|K] = x @ [Wq|Wk] immediately before flash (QKb hot per-XCD in L2)
  gemm256_kernel<<<dim3(16, 16), 512, 0, stream>>>(xb, Wtq, QKb, 4096, 4096, 2048);

  flash_diff_kernel<<<512, 256, 0, stream>>>(QKb, Vt, o12b);
  combine_kernel<<<32768, 256, 0, stream>>>(o12b, lamp, g, ob);
  gemm_bt_kernel<0><<<dim3(16, 32), 256, 0, stream>>>(ob, Wto, (float*)d_out, 4096, 2048, 2048);
}

// Round 7
// 380.611 us; speedup vs baseline: 1.0565x; 1.0382x over previous
//
#include <hip/hip_runtime.h>
#include <stdint.h>
#include <math.h>

// ---------------------------------------------------------------------------
// MultiheadSdpaDiff3 round 11.
// - flash2: both differential components (c=0,1) fused in one 512-thr block
//   (waves 0-3 = c0, 4-7 = c1): V staged once, K/V double-buffered, ONE
//   barrier per 64-col step, combine+RMSNorm fused into the epilogue
//   (combine_kernel deleted, o12b eliminated).
// - gemm256 (QKb), gemm_bt BK=64 (Vt, out), prep, XCD=h locality: round 10.
// ws layout (bytes):
//   xb   @ 0          : 16777216   (x as bf16 [4096][2048])
//   Wtq  @ 16777216   : 8388608    (Wq^T bf16 [N][K])
//   Wtk  @ 25165824   : 8388608    (contiguous after Wtq -> merged QK gemm)
//   Wtv  @ 33554432   : 8388608
//   Wto  @ 41943040   : 8388608
//   QKb  @ 50331648   : 33554432   (bf16 [4096][4096]: cols 0-2047 Q, 2048-4095 K)
//   Vt   @ 83886080   : 16777216   (bf16 [2048 e][4096 bt] = V^T, from gemm)
//   ob   @ 134217728  : 16777216   (combined+rmsnormed bf16 [4096][2048])
//   lam  @ 150994944  : 256
// ---------------------------------------------------------------------------

typedef unsigned short u16;
typedef short bf16x8 __attribute__((ext_vector_type(8)));
typedef float f32x4 __attribute__((ext_vector_type(4)));

typedef uint32_t __attribute__((address_space(1))) as1_u32;
typedef uint32_t __attribute__((address_space(3))) as3_u32;

#define LAMBDA_INIT 0.78360576653162453f

__device__ __forceinline__ u16 f2bf(float f) {
  uint32_t u = __float_as_uint(f);
  u += 0x7FFFu + ((u >> 16) & 1u);   // RNE
  return (u16)(u >> 16);
}
__device__ __forceinline__ float bf2f(u16 v) {
  return __uint_as_float(((uint32_t)v) << 16);
}

__device__ __forceinline__ void async16(u16* lds, const u16* g) {
  __builtin_amdgcn_global_load_lds((const as1_u32*)(uintptr_t)g,
                                   (as3_u32*)(uint32_t)(uintptr_t)lds, 16, 0, 0);
}

__device__ __forceinline__ f32x4 mfma16(bf16x8 a, bf16x8 b, f32x4 c) {
  return __builtin_amdgcn_mfma_f32_16x16x32_bf16(a, b, c, 0, 0, 0);
}

// --------------------------- prep kernels ----------------------------------

__global__ void cast_x_kernel(const float* __restrict__ x, u16* __restrict__ xb, int n4) {
  int i = blockIdx.x * 256 + threadIdx.x;
  if (i < n4) {
    float4 v = ((const float4*)x)[i];
    ushort4 o;
    o.x = f2bf(v.x); o.y = f2bf(v.y); o.z = f2bf(v.z); o.w = f2bf(v.w);
    ((ushort4*)xb)[i] = o;
  }
}

// Wt[n][k] = bf16(W[k][n]); W is [2048][2048] fp32. 4 matrices via blockIdx.z.
__global__ void transpose_w4_kernel(const float* __restrict__ W0, const float* __restrict__ W1,
                                    const float* __restrict__ W2, const float* __restrict__ W3,
                                    u16* __restrict__ Wt4) {
  __shared__ float tile[32][33];
  int z = blockIdx.z;
  const float* W = (z == 0) ? W0 : (z == 1) ? W1 : (z == 2) ? W2 : W3;
  u16* Wt = Wt4 + (size_t)z * 4194304;
  int tx = threadIdx.x, ty = threadIdx.y;
  int c0 = blockIdx.x * 32, r0 = blockIdx.y * 32;
#pragma unroll
  for (int i = 0; i < 32; i += 8)
    tile[ty + i][tx] = W[(size_t)(r0 + ty + i) * 2048 + c0 + tx];
  __syncthreads();
#pragma unroll
  for (int i = 0; i < 32; i += 8)
    Wt[(size_t)(c0 + ty + i) * 2048 + r0 + tx] = f2bf(tile[tx][ty + i]);
}

__global__ void lam_kernel(const float* __restrict__ lq1, const float* __restrict__ lk1,
                           const float* __restrict__ lq2, const float* __restrict__ lk2,
                           float* __restrict__ out) {
  int L = threadIdx.x;  // 64 threads
  float d1 = lq1[L] * lk1[L] + lq1[L + 64] * lk1[L + 64];
  float d2 = lq2[L] * lk2[L] + lq2[L + 64] * lk2[L + 64];
#pragma unroll
  for (int m = 1; m < 64; m <<= 1) {
    d1 += __shfl_xor(d1, m);
    d2 += __shfl_xor(d2, m);
  }
  if (L == 0) out[0] = __expf(d1) - __expf(d2) + LAMBDA_INIT;
}

// ----------------- GEMM 256x256 deep-pipelined (GEMM1) ---------------------
// 512 thr = 8 waves (2M x 4N); per-wave C = 128x64. BK=32. LDS: 4-deep
// circular buffer; one barrier per K-tile; counted vmcnt(8) steady state.
// Linear dispatch on 16x16 grid: writer of col-tile bx on XCD bx&7 -> head
// h's Q (bx=h) and K (bx=8+h) tiles land in XCD h's L2; flash2 uses xcd=h.

__device__ __forceinline__ void stage256(const u16* base, int K, int k0, u16* lds, int t_) {
#pragma unroll
  for (int i = 0; i < 2; i++) {
    int s = t_ + i * 512;
    int row = s >> 2, gp = s & 3;
    int gs = gp ^ ((row >> 1) & 3);
    async16(&lds[s * 8], base + (size_t)row * K + k0 + gs * 8);
  }
}

__global__ __launch_bounds__(512, 2) void gemm256_kernel(const u16* __restrict__ A,
                                                         const u16* __restrict__ Bt,
                                                         u16* __restrict__ Cout,
                                                         int M, int N, int K) {
  __shared__ __attribute__((aligned(16))) u16 Ls[4][2][256 * 32];
  int t_ = threadIdx.x;
  int lane = t_ & 63, w = t_ >> 6;
  int lr = lane & 15, lq = lane >> 4;
  int m0 = blockIdx.y * 256, n0 = blockIdx.x * 256;
  int wm = (w >> 2) * 128, wn = (w & 3) * 64;
  const u16* Ab = A + (size_t)m0 * K;
  const u16* Bb = Bt + (size_t)n0 * K;
  int NT = K >> 5;
  f32x4 acc[8][4] = {};

#pragma unroll
  for (int p = 0; p < 3; p++) {
    stage256(Ab, K, p * 32, &Ls[p][0][0], t_);
    stage256(Bb, K, p * 32, &Ls[p][1][0], t_);
  }
  asm volatile("s_waitcnt vmcnt(8)" ::: "memory");   // tile 0 landed
  __builtin_amdgcn_s_barrier();
  __builtin_amdgcn_sched_barrier(0);

#pragma unroll 1
  for (int t = 0; t < NT; t++) {
    int d = t & 3;
    const u16* As_ = &Ls[d][0][0];
    const u16* Bs_ = &Ls[d][1][0];
    bool stg = (t + 3 < NT);
    int k0n = (t + 3) * 32;
    int dn = (t + 3) & 3;

    bf16x8 b4[4], a0[4];
#pragma unroll
    for (int nf = 0; nf < 4; nf++) {
      int rb = wn + nf * 16 + lr;
      b4[nf] = *(const bf16x8*)&Bs_[rb * 32 + (lq ^ ((rb >> 1) & 3)) * 8];
    }
#pragma unroll
    for (int mf = 0; mf < 4; mf++) {
      int ra = wm + mf * 16 + lr;
      a0[mf] = *(const bf16x8*)&As_[ra * 32 + (lq ^ ((ra >> 1) & 3)) * 8];
    }
    if (stg) stage256(Ab, K, k0n, &Ls[dn][0][0], t_);
    __builtin_amdgcn_s_setprio(1);
#pragma unroll
    for (int mf = 0; mf < 4; mf++)
#pragma unroll
      for (int nf = 0; nf < 4; nf++)
        acc[mf][nf] = mfma16(a0[mf], b4[nf], acc[mf][nf]);
    __builtin_amdgcn_s_setprio(0);

    bf16x8 a1[4];
#pragma unroll
    for (int mf = 0; mf < 4; mf++) {
      int ra = wm + 64 + mf * 16 + lr;
      a1[mf] = *(const bf16x8*)&As_[ra * 32 + (lq ^ ((ra >> 1) & 3)) * 8];
    }
    if (stg) stage256(Bb, K, k0n, &Ls[dn][1][0], t_);
    __builtin_amdgcn_s_setprio(1);
#pragma unroll
    for (int mf = 0; mf < 4; mf++)
#pragma unroll
      for (int nf = 0; nf < 4; nf++)
        acc[4 + mf][nf] = mfma16(a1[mf], b4[nf], acc[4 + mf][nf]);
    __builtin_amdgcn_s_setprio(0);

    if (t < NT - 3)      asm volatile("s_waitcnt vmcnt(8)" ::: "memory");
    else if (t < NT - 2) asm volatile("s_waitcnt vmcnt(4)" ::: "memory");
    else                 asm volatile("s_waitcnt vmcnt(0)" ::: "memory");
    __builtin_amdgcn_s_barrier();
    __builtin_amdgcn_sched_barrier(0);
  }

#pragma unroll
  for (int mf = 0; mf < 8; mf++)
#pragma unroll
    for (int nf = 0; nf < 4; nf++)
#pragma unroll
      for (int r = 0; r < 4; r++) {
        int row = m0 + wm + mf * 16 + lq * 4 + r;
        int col = n0 + wn + nf * 16 + lr;
        Cout[(size_t)row * N + col] = f2bf(acc[mf][nf][r]);
      }
}

// --------------------------- GEMM (m97 + BK=64 + swizzle) ------------------
// Used for GEMM2/3 (round-8 proven config).
template <int OUT_BF16>
__global__ __launch_bounds__(256, 3) void gemm_bt_kernel(const u16* __restrict__ A,
                                                         const u16* __restrict__ Bt,
                                                         void* __restrict__ Cout,
                                                         int M, int N, int K) {
  __shared__ __attribute__((aligned(16))) u16 As[128 * 64];
  __shared__ __attribute__((aligned(16))) u16 Bs[128 * 64];
  int t = threadIdx.x;
  int lane = t & 63, w = t >> 6;
  int lr = lane & 15, lq = lane >> 4;
  int m0 = blockIdx.y * 128, n0 = blockIdx.x * 128;
  int wm = (w >> 1) * 64, wn = (w & 1) * 64;
  const u16* Ab = A + (size_t)m0 * K;
  const u16* Bb = Bt + (size_t)n0 * K;
  f32x4 acc[4][4] = {};

  for (int k0 = 0; k0 < K; k0 += 64) {
    __syncthreads();
#pragma unroll
    for (int i = 0; i < 4; i++) {
      int q = t + i * 256;
      int row = q >> 3, gp = q & 7;
      int gg = gp ^ (row & 7);
      async16(&As[q * 8], Ab + (size_t)row * K + k0 + gg * 8);
      async16(&Bs[q * 8], Bb + (size_t)row * K + k0 + gg * 8);
    }
    __syncthreads();
#pragma unroll
    for (int kk = 0; kk < 2; kk++) {
      bf16x8 a[4], b[4];
#pragma unroll
      for (int mi = 0; mi < 4; mi++) {
        int ra = wm + mi * 16 + lr;
        int rb = wn + mi * 16 + lr;
        a[mi] = *(const bf16x8*)&As[ra * 64 + ((kk * 4 + lq) ^ (ra & 7)) * 8];
        b[mi] = *(const bf16x8*)&Bs[rb * 64 + ((kk * 4 + lq) ^ (rb & 7)) * 8];
      }
#pragma unroll
      for (int mi = 0; mi < 4; mi++)
#pragma unroll
        for (int ni = 0; ni < 4; ni++)
          acc[mi][ni] = mfma16(a[mi], b[ni], acc[mi][ni]);
    }
  }
#pragma unroll
  for (int mi = 0; mi < 4; mi++) {
#pragma unroll
    for (int ni = 0; ni < 4; ni++) {
#pragma unroll
      for (int r = 0; r < 4; r++) {
        int row = m0 + wm + mi * 16 + lq * 4 + r;
        int col = n0 + wn + ni * 16 + lr;
        if (OUT_BF16)
          ((u16*)Cout)[(size_t)row * N + col] = f2bf(acc[mi][ni][r]);
        else
          ((float*)Cout)[(size_t)row * N + col] = acc[mi][ni][r];
      }
    }
  }
}

// --------------------- flash attention, fused differential ------------------
// 256 blocks x 512 thr (8 waves). Waves 0-3: c=0, waves 4-7: c=1 of the SAME
// (b,h) 64-row q-tile -> V staged once for both. K tile [64 kv][256 d]
// (d 0-127 = c0, 128-255 = c1), V tile [256 e][64 kv], both double-buffered;
// stage(j+1) issued at step start, ONE __syncthreads per step (drains DMA
// issued a full compute-phase earlier). Softmax/P/PV per wave = round-7
// verified body. Epilogue: c1 waves write normalized o2 (bf16) into reused
// K LDS; c0 waves compute o1 - lam*o2, RMSNorm (shfl within 16-lane group),
// scale by g, write ob directly. combine_kernel is gone.
// K granule swizzle: low-3 XOR row&7 (bits 3-4 = ks-high/c untouched).
// V granule swizzle: XOR e&7 (as round 7). P per wave [16][88].

struct F2Ctx {
  const u16* Qbase;   // own c
  const u16* Kbase;   // both c (256 cols)
  const u16* Vbase;
  int t, w, wl, c, lr, lq;
};

__device__ __forceinline__ void stage_k2(const F2Ctx& cx, int jc, u16* Kb) {
#pragma unroll
  for (int i = 0; i < 4; i++) {
    int s = cx.t + i * 512;
    int row = s >> 5, gp = s & 31;
    int gg = (gp & 24) | ((gp & 7) ^ (row & 7));
    async16(&Kb[s * 8], cx.Kbase + (size_t)(jc + row) * 4096 + gg * 8);
  }
}

__device__ __forceinline__ void stage_v2(const F2Ctx& cx, int jc, u16* Vb) {
#pragma unroll
  for (int i = 0; i < 4; i++) {
    int s = cx.t + i * 512;
    int e = s >> 3, gp = s & 7;
    int gg = gp ^ (e & 7);
    async16(&Vb[s * 8], cx.Vbase + (size_t)e * 4096 + jc + gg * 8);
  }
}

__global__ __launch_bounds__(512, 2) void flash2_kernel(const u16* __restrict__ QKb,
                                                        const u16* __restrict__ Vt,
                                                        const float* __restrict__ lamp,
                                                        const float* __restrict__ g,
                                                        u16* __restrict__ ob) {
  __shared__ __attribute__((aligned(16))) u16 Ks[2][64 * 256];
  __shared__ __attribute__((aligned(16))) u16 Vs[2][256 * 64];
  __shared__ __attribute__((aligned(16))) u16 Ps[8][16 * 88];
  __shared__ float gsh[256];

  int t = threadIdx.x;
  F2Ctx cx;
  cx.t = t; cx.w = t >> 6; cx.wl = cx.w & 3; cx.c = cx.w >> 2;
  cx.lr = t & 15; cx.lq = (t >> 4) & 3;

  if (t < 256) gsh[t] = g[t];

  // XCD = h decode (producer-aligned): idx = 0..255
  int idx = blockIdx.x;
  int h = idx & 7;
  int slot = idx >> 3;        // 0..31
  int pairI = slot & 15;
  int b = slot >> 4;          // 0..1

  const u16* QKbh = QKb + (size_t)b * 2048 * 4096 + h * 256;
  cx.Qbase = QKbh + cx.c * 128;
  cx.Kbase = QKbh + 2048;
  cx.Vbase = Vt + (size_t)(h * 256) * 4096 + b * 2048;
  u16* obp = ob + (size_t)b * 2048 * 2048 + h * 256;
  u16* PsW = Ps[cx.w];

  const float k2 = 0.12753257550036097f;   // log2(e)/sqrt(128)
  const bf16x8 onesb = {0x3F80, 0x3F80, 0x3F80, 0x3F80,
                        0x3F80, 0x3F80, 0x3F80, 0x3F80};

#pragma unroll 1
  for (int phase = 0; phase < 2; phase++) {
    int qi = phase ? (31 - pairI) : pairI;
    int q0 = qi * 64;
    int nst = qi + 1;

    bf16x8 qa[4];
#pragma unroll
    for (int ks = 0; ks < 4; ks++)
      qa[ks] = *(const bf16x8*)&cx.Qbase[(size_t)(q0 + cx.wl * 16 + cx.lr) * 4096 +
                                         ks * 32 + cx.lq * 8];

    f32x4 acc[16] = {};
    f32x4 lacc = {};
    float m_ = -INFINITY;
    int rowmax = q0 + cx.wl * 16 + 15;

    // prologue: stage tile 0 into buf 0, drain
    stage_k2(cx, 0, Ks[0]);
    stage_v2(cx, 0, Vs[0]);
    __syncthreads();

#pragma unroll 1
    for (int j = 0; j < nst; j++) {
      int jc = j * 64;
      if (j + 1 < nst) {                       // prefetch next tile
        stage_k2(cx, jc + 64, Ks[(j + 1) & 1]);
        stage_v2(cx, jc + 64, Vs[(j + 1) & 1]);
      }
      const u16* Kc = Ks[j & 1];
      const u16* Vc = Vs[j & 1];

      bool act = (jc <= rowmax);               // wave-uniform
      if (act) {
        // S = Q K^T : 16 rows x 64 cols per wave (own c)
        f32x4 sacc[4] = {};
#pragma unroll
        for (int ks = 0; ks < 4; ks++) {
#pragma unroll
          for (int ni = 0; ni < 4; ni++) {
            int row = ni * 16 + cx.lr;
            int gk = cx.c * 16 + ks * 4 + cx.lq;
            int gp = (gk & 24) | ((gk & 7) ^ (row & 7));
            bf16x8 kb = *(const bf16x8*)&Kc[row * 256 + gp * 8];
            sacc[ni] = mfma16(qa[ks], kb, sacc[ni]);
          }
        }

        float s2[4][4];
        bool diag = (jc + 63 > q0 + cx.wl * 16);
#pragma unroll
        for (int ni = 0; ni < 4; ni++)
#pragma unroll
          for (int r = 0; r < 4; r++) {
            float v = sacc[ni][r] * k2;
            if (diag) {
              int colg = jc + ni * 16 + cx.lr;
              int rowg = q0 + cx.wl * 16 + cx.lq * 4 + r;
              if (colg > rowg) v = -INFINITY;
            }
            s2[ni][r] = v;
          }

        // defer-max (T13)
        float sm = fmaxf(
            fmaxf(fmaxf(fmaxf(s2[0][0], s2[0][1]), fmaxf(s2[0][2], s2[0][3])),
                  fmaxf(fmaxf(s2[1][0], s2[1][1]), fmaxf(s2[1][2], s2[1][3]))),
            fmaxf(fmaxf(fmaxf(s2[2][0], s2[2][1]), fmaxf(s2[2][2], s2[2][3])),
                  fmaxf(fmaxf(s2[3][0], s2[3][1]), fmaxf(s2[3][2], s2[3][3]))));
        float mo = m_;
        if (__any(sm > mo + 8.0f)) {
          float mv = sm;
          mv = fmaxf(mv, __shfl_xor(mv, 1));
          mv = fmaxf(mv, __shfl_xor(mv, 2));
          mv = fmaxf(mv, __shfl_xor(mv, 4));
          mv = fmaxf(mv, __shfl_xor(mv, 8));
          mv = fmaxf(mv, __shfl_xor(mv, 16));
          mv = fmaxf(mv, __shfl_xor(mv, 32));
          float mn = fmaxf(mo, mv);
          float a = __builtin_amdgcn_exp2f(mo - mn);   // -inf -> 0
#pragma unroll
          for (int ei = 0; ei < 16; ei++)
#pragma unroll
            for (int r = 0; r < 4; r++) acc[ei][r] *= a;
#pragma unroll
          for (int r = 0; r < 4; r++) lacc[r] *= a;
          m_ = mn;
          mo = mn;
        }

        // P (truncated bf16; consistent with l via ones-MFMA)
#pragma unroll
        for (int ni = 0; ni < 4; ni++)
#pragma unroll
          for (int r = 0; r < 4; r++) {
            float p = __builtin_amdgcn_exp2f(s2[ni][r] - mo);
            PsW[(cx.lq * 4 + r) * 88 + ni * 16 + cx.lr] =
                (u16)(__float_as_uint(p) >> 16);
          }

        // PV (P wave-private; same-wave LDS write->read)
        bf16x8 pa0 = *(const bf16x8*)&PsW[cx.lr * 88 + cx.lq * 8];
        bf16x8 pa1 = *(const bf16x8*)&PsW[cx.lr * 88 + 32 + cx.lq * 8];
        __builtin_amdgcn_s_setprio(1);
#pragma unroll
        for (int ei = 0; ei < 16; ei++) {
          int e = ei * 16 + cx.lr;
          int g0 = cx.lq ^ (e & 7);
          int g1 = g0 ^ 4;
          bf16x8 vb0 = *(const bf16x8*)&Vc[e * 64 + g0 * 8];
          bf16x8 vb1 = *(const bf16x8*)&Vc[e * 64 + g1 * 8];
          acc[ei] = mfma16(pa0, vb0, acc[ei]);
          acc[ei] = mfma16(pa1, vb1, acc[ei]);
        }
        lacc = mfma16(pa0, onesb, lacc);
        lacc = mfma16(pa1, onesb, lacc);
        __builtin_amdgcn_s_setprio(0);
      }

      __syncthreads();   // joins all waves; drains own DMA for tile j+1
    }

    // ---- fused combine + RMSNorm epilogue ----
    u16* Os = (u16*)&Ks[0][0];          // [64][256] bf16 o2 (K reads all done)
    if (cx.c == 1) {
#pragma unroll
      for (int r = 0; r < 4; r++) {
        float inv = 1.0f / lacc[r];
        int rowL = cx.wl * 16 + cx.lq * 4 + r;
#pragma unroll
        for (int ei = 0; ei < 16; ei++)
          Os[rowL * 256 + ei * 16 + cx.lr] = f2bf(acc[ei][r] * inv);
      }
    }
    __syncthreads();
    if (cx.c == 0) {
      float lam = lamp[0];
#pragma unroll
      for (int r = 0; r < 4; r++) {
        float inv = 1.0f / lacc[r];
        int rowL = cx.wl * 16 + cx.lq * 4 + r;
        float vv[16];
        float ss = 0.0f;
#pragma unroll
        for (int ei = 0; ei < 16; ei++) {
          float o1 = acc[ei][r] * inv;
          float o2 = bf2f(Os[rowL * 256 + ei * 16 + cx.lr]);
          float v = o1 - lam * o2;
          vv[ei] = v;
          ss += v * v;
        }
        ss += __shfl_xor(ss, 1);
        ss += __shfl_xor(ss, 2);
        ss += __shfl_xor(ss, 4);
        ss += __shfl_xor(ss, 8);
        float scale = rsqrtf(ss * (1.0f / 256.0f) + 1e-5f) * (1.0f - LAMBDA_INIT);
        size_t rowG = (size_t)(q0 + rowL) * 2048;
#pragma unroll
        for (int ei = 0; ei < 16; ei++)
          obp[rowG + ei * 16 + cx.lr] = f2bf(vv[ei] * scale * gsh[ei * 16 + cx.lr]);
      }
    }
    __syncthreads();   // Os (= Ks[0]) free before next phase's staging
  }
}

// ---------------------------------------------------------------------------

extern "C" void kernel_launch(void* const* d_in, const int* in_sizes, int n_in,
                              void* d_out, int out_size, void* d_ws, size_t ws_size,
                              hipStream_t stream) {
  const float* x   = (const float*)d_in[0];
  const float* Wq  = (const float*)d_in[1];
  const float* Wk  = (const float*)d_in[2];
  const float* Wv  = (const float*)d_in[3];
  const float* Wo  = (const float*)d_in[4];
  const float* lq1 = (const float*)d_in[5];
  const float* lk1 = (const float*)d_in[6];
  const float* lq2 = (const float*)d_in[7];
  const float* lk2 = (const float*)d_in[8];
  const float* g   = (const float*)d_in[9];

  char* ws = (char*)d_ws;
  u16* xb    = (u16*)(ws);
  u16* Wtq   = (u16*)(ws + 16777216);
  u16* Wtv   = (u16*)(ws + 33554432);
  u16* Wto   = (u16*)(ws + 41943040);
  u16* QKb   = (u16*)(ws + 50331648);
  u16* Vt    = (u16*)(ws + 83886080);
  u16* ob    = (u16*)(ws + 134217728);
  float* lamp = (float*)(ws + 150994944);

  cast_x_kernel<<<8192, 256, 0, stream>>>(x, xb, 2097152);
  transpose_w4_kernel<<<dim3(64, 64, 4), dim3(32, 8), 0, stream>>>(Wq, Wk, Wv, Wo, Wtq);
  lam_kernel<<<1, 64, 0, stream>>>(lq1, lk1, lq2, lk2, lamp);

  // V^T first: C[e][bt] = sum_k Wv[k][e] x[bt][k]  (M=2048, N=4096)
  gemm_bt_kernel<1><<<dim3(32, 16), 256, 0, stream>>>(Wtv, xb, Vt, 2048, 4096, 2048);
  // [Q|K] = x @ [Wq|Wk] immediately before flash (QKb hot per-XCD in L2)
  gemm256_kernel<<<dim3(16, 16), 512, 0, stream>>>(xb, Wtq, QKb, 4096, 4096, 2048);

  flash2_kernel<<<256, 512, 0, stream>>>(QKb, Vt, lamp, g, ob);
  gemm_bt_kernel<0><<<dim3(16, 32), 256, 0, stream>>>(ob, Wto, (float*)d_out, 4096, 2048, 2048);
}